// Round 3
// baseline (423.849 us; speedup 1.0000x reference)
//
#include <hip/hip_runtime.h>
#include <hip/hip_bf16.h>
#include <cstdint>
#include <cstddef>

#define N_NODES 50000
#define N_EDGES 800000
#define IN_DIM 256
#define HC 128          // HEADS*OUT_DIM
#define HEADS 4
#define NEG_SLOPE 0.2f
#define LN_EPS 1e-5f

typedef _Float16 f16x8 __attribute__((ext_vector_type(8)));
typedef _Float16 f16x2 __attribute__((ext_vector_type(2)));
typedef float f32x4 __attribute__((ext_vector_type(4)));

__device__ __forceinline__ float lrelu(float x) { return x > 0.f ? x : NEG_SLOPE * x; }

// K1: h = x@W via MFMA f16 (fp32 accumulate), fused a_s/a_d dots.
// Block: 256 thr = 4 waves, 64 rows (16/wave). W^T staged in LDS as f16,
// XOR-swizzled 16B groups so B-frag ds_read_b128 is conflict-free.
// Logical Wt[n][k], k=8g+j  ->  physical half index n*256 + (g^(n&7))*8 + j.
__global__ __launch_bounds__(256) void k1_mfma(
    const float* __restrict__ x, const float* __restrict__ W,
    const float* __restrict__ att_src, const float* __restrict__ att_dst,
    _Float16* __restrict__ h16, float* __restrict__ a_s, float* __restrict__ a_d)
{
    __shared__ _Float16 Wt[128 * 256];   // 64 KB
    const int tid = threadIdx.x;

    for (int i = tid; i < IN_DIM * HC; i += 256) {
        int k = i >> 7, n = i & 127;           // W[k][n], coalesced read
        int g = k >> 3, j = k & 7;
        Wt[n * 256 + ((g ^ (n & 7)) << 3) + j] = (_Float16)W[i];
    }
    __syncthreads();

    const int wave = tid >> 6;
    const int lane = tid & 63;
    const int col  = lane & 15;
    const int quad = lane >> 4;
    const int m0   = blockIdx.x * 64 + wave * 16;

    const int rowA = min(m0 + col, N_NODES - 1);       // clamp tail; stores guarded
    const float* xrow = x + (size_t)rowA * IN_DIM;

    f32x4 acc[8];
#pragma unroll
    for (int nt = 0; nt < 8; ++nt) acc[nt] = (f32x4){0.f, 0.f, 0.f, 0.f};

#pragma unroll
    for (int kt = 0; kt < 8; ++kt) {
        const int k0 = kt * 32 + quad * 8;
        float4 xa = *(const float4*)(xrow + k0);
        float4 xb = *(const float4*)(xrow + k0 + 4);
        f16x8 a;
        a[0] = (_Float16)xa.x; a[1] = (_Float16)xa.y;
        a[2] = (_Float16)xa.z; a[3] = (_Float16)xa.w;
        a[4] = (_Float16)xb.x; a[5] = (_Float16)xb.y;
        a[6] = (_Float16)xb.z; a[7] = (_Float16)xb.w;
        const int g = kt * 4 + quad;
#pragma unroll
        for (int nt = 0; nt < 8; ++nt) {
            int n = nt * 16 + col;
            f16x8 b = *(const f16x8*)&Wt[n * 256 + ((g ^ (n & 7)) << 3)];
            acc[nt] = __builtin_amdgcn_mfma_f32_16x16x32_f16(a, b, acc[nt], 0, 0, 0);
        }
    }

    // epilogue: h16 store + per-(row,head) att dots
    float pS[4][4], pD[4][4];
#pragma unroll
    for (int hd = 0; hd < 4; ++hd)
#pragma unroll
        for (int r = 0; r < 4; ++r) { pS[hd][r] = 0.f; pD[hd][r] = 0.f; }

#pragma unroll
    for (int nt = 0; nt < 8; ++nt) {
        int ch = nt * 16 + col;
        float sv = att_src[ch], dv = att_dst[ch];
        int hd = nt >> 1;
#pragma unroll
        for (int r = 0; r < 4; ++r) {
            int row = m0 + quad * 4 + r;
            if (row < N_NODES) h16[(size_t)row * HC + ch] = (_Float16)acc[nt][r];
            pS[hd][r] += acc[nt][r] * sv;
            pD[hd][r] += acc[nt][r] * dv;
        }
    }
#pragma unroll
    for (int off = 1; off < 16; off <<= 1) {
#pragma unroll
        for (int hd = 0; hd < 4; ++hd)
#pragma unroll
            for (int r = 0; r < 4; ++r) {
                pS[hd][r] += __shfl_xor(pS[hd][r], off, 16);
                pD[hd][r] += __shfl_xor(pD[hd][r], off, 16);
            }
    }
    if (col == 0) {
#pragma unroll
        for (int r = 0; r < 4; ++r) {
            int row = m0 + quad * 4 + r;
            if (row < N_NODES) {
#pragma unroll
                for (int hd = 0; hd < 4; ++hd) {
                    a_s[row * HEADS + hd] = pS[hd][r];
                    a_d[row * HEADS + hd] = pD[hd][r];
                }
            }
        }
    }
}

// ---- counting sort of edges by dst ----
__global__ __launch_bounds__(256) void k_zero(int* __restrict__ counts) {
    int i = blockIdx.x * 256 + threadIdx.x;
    if (i < N_NODES) counts[i] = 0;
}
__global__ __launch_bounds__(256) void k_hist(const int* __restrict__ ei,
                                              int* __restrict__ counts) {
    int e = blockIdx.x * 256 + threadIdx.x;
    if (e < N_EDGES) atomicAdd(&counts[ei[N_EDGES + e]], 1);
}
__global__ __launch_bounds__(256) void k_scan1(const int* __restrict__ counts,
                                               int* __restrict__ starts,
                                               int* __restrict__ bsum) {
    __shared__ int s[256];
    int i = blockIdx.x * 256 + threadIdx.x;
    int v = (i < N_NODES) ? counts[i] : 0;
    s[threadIdx.x] = v; __syncthreads();
#pragma unroll
    for (int off = 1; off < 256; off <<= 1) {
        int t = (threadIdx.x >= off) ? s[threadIdx.x - off] : 0;
        __syncthreads();
        s[threadIdx.x] += t;
        __syncthreads();
    }
    if (i < N_NODES) starts[i] = s[threadIdx.x] - v;
    if (threadIdx.x == 255) bsum[blockIdx.x] = s[255];
}
__global__ __launch_bounds__(256) void k_scan2(int* __restrict__ bsum, int nb) {
    __shared__ int s[256];
    int v = (threadIdx.x < nb) ? bsum[threadIdx.x] : 0;
    s[threadIdx.x] = v; __syncthreads();
#pragma unroll
    for (int off = 1; off < 256; off <<= 1) {
        int t = (threadIdx.x >= off) ? s[threadIdx.x - off] : 0;
        __syncthreads();
        s[threadIdx.x] += t;
        __syncthreads();
    }
    if (threadIdx.x < nb) bsum[threadIdx.x] = s[threadIdx.x] - v;
}
__global__ __launch_bounds__(256) void k_scan3(int* __restrict__ starts,
                                               const int* __restrict__ bsum,
                                               int* __restrict__ cursor) {
    int i = blockIdx.x * 256 + threadIdx.x;
    if (i < N_NODES) {
        int s2 = starts[i] + bsum[blockIdx.x];
        starts[i] = s2;
        cursor[i] = s2;
    }
}
__global__ __launch_bounds__(256) void k_scatter(const int* __restrict__ ei,
                                                 int* __restrict__ cursor,
                                                 int* __restrict__ ssrc) {
    int e = blockIdx.x * 256 + threadIdx.x;
    if (e >= N_EDGES) return;
    int src = ei[e], dst = ei[N_EDGES + e];
    int p = atomicAdd(&cursor[dst], 1);
    ssrc[p] = src;
}

// K5: one wave per node. Lane c owns channel pair (2c,2c+1) -> single head per
// lane -> ONE exp per edge-lane. h is f16 packed half2. No atomics.
__global__ __launch_bounds__(256) void k_gather(
    const int* __restrict__ starts, const int* __restrict__ counts,
    const int* __restrict__ ssrc, const float* __restrict__ a_s,
    const float* __restrict__ a_d, const _Float16* __restrict__ h16,
    const float* __restrict__ bias, const float* __restrict__ gamma,
    const float* __restrict__ beta, float* __restrict__ out)
{
    int gid = blockIdx.x * 256 + threadIdx.x;
    int n = gid >> 6, lane = gid & 63;
    if (n >= N_NODES) return;

    const int beg = starts[n], deg = counts[n];
    const f16x2* h2 = (const f16x2*)h16;   // 64 half2 per node row

    float4 adN = *(const float4*)(a_d + (size_t)n * HEADS);
    float4 asN = *(const float4*)(a_s + (size_t)n * HEADS);
    // head of this lane's channel pair: lane>>4
    const float adH = (lane & 32) ? ((lane & 16) ? adN.w : adN.z)
                                  : ((lane & 16) ? adN.y : adN.x);
    const float asH = (lane & 32) ? ((lane & 16) ? asN.w : asN.z)
                                  : ((lane & 16) ? asN.y : asN.x);
    const float lSelf = lrelu(asH + adH);

    // ---- pass A: per-head max over segment (self-loop seeds) ----
    float m = lSelf;
    for (int base = 0; base < deg; base += 64) {
        int nc = min(64, deg - base);
        int sv = (lane < nc) ? ssrc[beg + base + lane] : 0;
        for (int j = 0; j < nc; ++j) {
            int src = __shfl(sv, j, 64);
            float4 as = *(const float4*)(a_s + (size_t)src * HEADS); // broadcast
            float asv = (lane & 32) ? ((lane & 16) ? as.w : as.z)
                                    : ((lane & 16) ? as.y : as.x);
            m = fmaxf(m, lrelu(asv + adH));
        }
    }

    // ---- pass B: exp weights, denom, register accumulate ----
    const float wSelf = __expf(lSelf - m);
    float den = wSelf;
    f16x2 hv = h2[(size_t)n * 64 + lane];
    float acc0 = (float)hv[0] * wSelf;
    float acc1 = (float)hv[1] * wSelf;
    for (int base = 0; base < deg; base += 64) {
        int nc = min(64, deg - base);
        int sv = (lane < nc) ? ssrc[beg + base + lane] : 0;
        for (int j = 0; j < nc; ++j) {
            int src = __shfl(sv, j, 64);
            float4 as = *(const float4*)(a_s + (size_t)src * HEADS); // broadcast
            float asv = (lane & 32) ? ((lane & 16) ? as.w : as.z)
                                    : ((lane & 16) ? as.y : as.x);
            float w = __expf(lrelu(asv + adH) - m);
            f16x2 hx = h2[(size_t)src * 64 + lane];   // 256B coalesced
            acc0 += (float)hx[0] * w;
            acc1 += (float)hx[1] * w;
            den += w;
        }
    }

    // ---- epilogue: normalize + bias + LayerNorm + ELU ----
    float2 bv = ((const float2*)bias)[lane];
    float2 gv = ((const float2*)gamma)[lane];
    float2 be = ((const float2*)beta)[lane];
    float v0 = acc0 / den + bv.x;
    float v1 = acc1 / den + bv.y;
    float s = v0 + v1;
#pragma unroll
    for (int off = 32; off; off >>= 1) s += __shfl_xor(s, off, 64);
    float mu = s * (1.f / 128.f);
    float d0 = v0 - mu, d1 = v1 - mu;
    float q = d0 * d0 + d1 * d1;
#pragma unroll
    for (int off = 32; off; off >>= 1) q += __shfl_xor(q, off, 64);
    float rs = rsqrtf(q * (1.f / 128.f) + LN_EPS);
    float o0 = d0 * rs * gv.x + be.x;
    float o1 = d1 * rs * gv.y + be.y;
    o0 = o0 > 0.f ? o0 : __expf(o0) - 1.f;
    o1 = o1 > 0.f ? o1 : __expf(o1) - 1.f;
    float2 ov = {o0, o1};
    ((float2*)out)[(size_t)n * 64 + lane] = ov;
}

extern "C" void kernel_launch(void* const* d_in, const int* in_sizes, int n_in,
                              void* d_out, int out_size, void* d_ws, size_t ws_size,
                              hipStream_t stream) {
    const float* x       = (const float*)d_in[0];
    const int*   ei      = (const int*)d_in[1];   // [2, E] int32: row0=src, row1=dst
    const float* W       = (const float*)d_in[2];
    const float* att_src = (const float*)d_in[3];
    const float* att_dst = (const float*)d_in[4];
    const float* bias    = (const float*)d_in[5];
    const float* gamma   = (const float*)d_in[6];
    const float* beta    = (const float*)d_in[7];
    float* out = (float*)d_out;

    char* ws = (char*)d_ws;
    // layout (16B-aligned): h16 12.8MB | a_s .8MB | a_d .8MB | ssrc 3.2MB
    //                       | counts .2MB | starts .2MB | cursor .2MB | bsum 1KB
    _Float16* h16    = (_Float16*)(ws);
    float*    a_s    = (float*)(ws + 12800000);
    float*    a_d    = (float*)(ws + 13600000);
    int*      ssrc   = (int*)  (ws + 14400000);
    int*      counts = (int*)  (ws + 17600000);
    int*      starts = (int*)  (ws + 17800000);
    int*      cursor = (int*)  (ws + 18000000);
    int*      bsum   = (int*)  (ws + 18200000);

    const int NB = (N_NODES + 255) / 256;   // 196 scan blocks (<=256)

    k1_mfma<<<(N_NODES + 63) / 64, 256, 0, stream>>>(x, W, att_src, att_dst, h16, a_s, a_d);
    k_zero<<<NB, 256, 0, stream>>>(counts);
    k_hist<<<(N_EDGES + 255) / 256, 256, 0, stream>>>(ei, counts);
    k_scan1<<<NB, 256, 0, stream>>>(counts, starts, bsum);
    k_scan2<<<1, 256, 0, stream>>>(bsum, NB);
    k_scan3<<<NB, 256, 0, stream>>>(starts, bsum, cursor);
    k_scatter<<<(N_EDGES + 255) / 256, 256, 0, stream>>>(ei, cursor, ssrc);
    k_gather<<<(N_NODES * 64 + 255) / 256, 256, 0, stream>>>(
        starts, counts, ssrc, a_s, a_d, h16, bias, gamma, beta, out);
}

// Round 4
// 355.462 us; speedup vs baseline: 1.1924x; 1.1924x over previous
//
#include <hip/hip_runtime.h>
#include <hip/hip_bf16.h>
#include <cstdint>
#include <cstddef>

#define N_NODES 50000
#define N_EDGES 800000
#define IN_DIM 256
#define HC 128          // HEADS*OUT_DIM
#define HEADS 4
#define NEG_SLOPE 0.2f
#define LN_EPS 1e-5f

typedef _Float16 f16x8 __attribute__((ext_vector_type(8)));
typedef _Float16 f16x2 __attribute__((ext_vector_type(2)));
typedef float f32x4 __attribute__((ext_vector_type(4)));

__device__ __forceinline__ float lrelu(float x) { return x > 0.f ? x : NEG_SLOPE * x; }

// K1: h = x@W via MFMA f16 (fp32 accumulate), fused a_s/a_d dots.
// Also zeroes the histogram (saves a launch; k_hist runs after in stream order).
__global__ __launch_bounds__(256) void k1_mfma(
    const float* __restrict__ x, const float* __restrict__ W,
    const float* __restrict__ att_src, const float* __restrict__ att_dst,
    _Float16* __restrict__ h16, float* __restrict__ a_s, float* __restrict__ a_d,
    int* __restrict__ counts)
{
    __shared__ _Float16 Wt[128 * 256];   // 64 KB
    const int tid = threadIdx.x;

    int gz = blockIdx.x * 256 + tid;
    if (gz < N_NODES) counts[gz] = 0;

    for (int i = tid; i < IN_DIM * HC; i += 256) {
        int k = i >> 7, n = i & 127;           // W[k][n], coalesced read
        int g = k >> 3, j = k & 7;
        Wt[n * 256 + ((g ^ (n & 7)) << 3) + j] = (_Float16)W[i];
    }
    __syncthreads();

    const int wave = tid >> 6;
    const int lane = tid & 63;
    const int col  = lane & 15;
    const int quad = lane >> 4;
    const int m0   = blockIdx.x * 64 + wave * 16;

    const int rowA = min(m0 + col, N_NODES - 1);       // clamp tail; stores guarded
    const float* xrow = x + (size_t)rowA * IN_DIM;

    f32x4 acc[8];
#pragma unroll
    for (int nt = 0; nt < 8; ++nt) acc[nt] = (f32x4){0.f, 0.f, 0.f, 0.f};

#pragma unroll
    for (int kt = 0; kt < 8; ++kt) {
        const int k0 = kt * 32 + quad * 8;
        float4 xa = *(const float4*)(xrow + k0);
        float4 xb = *(const float4*)(xrow + k0 + 4);
        f16x8 a;
        a[0] = (_Float16)xa.x; a[1] = (_Float16)xa.y;
        a[2] = (_Float16)xa.z; a[3] = (_Float16)xa.w;
        a[4] = (_Float16)xb.x; a[5] = (_Float16)xb.y;
        a[6] = (_Float16)xb.z; a[7] = (_Float16)xb.w;
        const int g = kt * 4 + quad;
#pragma unroll
        for (int nt = 0; nt < 8; ++nt) {
            int n = nt * 16 + col;
            f16x8 b = *(const f16x8*)&Wt[n * 256 + ((g ^ (n & 7)) << 3)];
            acc[nt] = __builtin_amdgcn_mfma_f32_16x16x32_f16(a, b, acc[nt], 0, 0, 0);
        }
    }

    // epilogue: h16 store + per-(row,head) att dots
    float pS[4][4], pD[4][4];
#pragma unroll
    for (int hd = 0; hd < 4; ++hd)
#pragma unroll
        for (int r = 0; r < 4; ++r) { pS[hd][r] = 0.f; pD[hd][r] = 0.f; }

#pragma unroll
    for (int nt = 0; nt < 8; ++nt) {
        int ch = nt * 16 + col;
        float sv = att_src[ch], dv = att_dst[ch];
        int hd = nt >> 1;
#pragma unroll
        for (int r = 0; r < 4; ++r) {
            int row = m0 + quad * 4 + r;
            if (row < N_NODES) h16[(size_t)row * HC + ch] = (_Float16)acc[nt][r];
            pS[hd][r] += acc[nt][r] * sv;
            pD[hd][r] += acc[nt][r] * dv;
        }
    }
#pragma unroll
    for (int off = 1; off < 16; off <<= 1) {
#pragma unroll
        for (int hd = 0; hd < 4; ++hd)
#pragma unroll
            for (int r = 0; r < 4; ++r) {
                pS[hd][r] += __shfl_xor(pS[hd][r], off, 16);
                pD[hd][r] += __shfl_xor(pD[hd][r], off, 16);
            }
    }
    if (col == 0) {
#pragma unroll
        for (int r = 0; r < 4; ++r) {
            int row = m0 + quad * 4 + r;
            if (row < N_NODES) {
#pragma unroll
                for (int hd = 0; hd < 4; ++hd) {
                    a_s[row * HEADS + hd] = pS[hd][r];
                    a_d[row * HEADS + hd] = pD[hd][r];
                }
            }
        }
    }
}

// histogram of dst
__global__ __launch_bounds__(256) void k_hist(const int* __restrict__ ei,
                                              int* __restrict__ counts) {
    int e = blockIdx.x * 256 + threadIdx.x;
    if (e < N_EDGES) atomicAdd(&counts[ei[N_EDGES + e]], 1);
}

// single-block exclusive scan of counts -> starts (+ cursor copy). 1024 threads,
// each owns a contiguous chunk of 49 counters.
__global__ __launch_bounds__(1024) void k_scan(const int* __restrict__ counts,
                                               int* __restrict__ starts,
                                               int* __restrict__ cursor) {
    __shared__ int part[1024];
    const int t = threadIdx.x;
    const int CH = (N_NODES + 1023) / 1024;   // 49
    const int b0 = t * CH;
    const int e0 = min(b0 + CH, N_NODES);
    int s = 0;
    for (int i = b0; i < e0; ++i) s += counts[i];
    part[t] = s;
    __syncthreads();
#pragma unroll
    for (int off = 1; off < 1024; off <<= 1) {
        int t2 = (t >= off) ? part[t - off] : 0;
        __syncthreads();
        part[t] += t2;
        __syncthreads();
    }
    int run = part[t] - s;                     // exclusive prefix of this chunk
    for (int i = b0; i < e0; ++i) {
        starts[i] = run;
        cursor[i] = run;
        run += counts[i];
    }
}

// scatter src + per-edge exp-weights (no-max softmax) into dst-sorted order.
// Edge-parallel: 800k threads fully hide the random-access latency here, so the
// serial gather loop doesn't have to compute exp at all.
__global__ __launch_bounds__(256) void k_scatter(
    const int* __restrict__ ei, int* __restrict__ cursor,
    const float* __restrict__ a_s, const float* __restrict__ a_d,
    int* __restrict__ ssrc, float4* __restrict__ sw)
{
    int e = blockIdx.x * 256 + threadIdx.x;
    if (e >= N_EDGES) return;
    int src = ei[e], dst = ei[N_EDGES + e];
    float4 s4 = *(const float4*)(a_s + (size_t)src * HEADS);   // L2-resident (800KB)
    float4 d4 = *(const float4*)(a_d + (size_t)dst * HEADS);
    float4 w4;
    w4.x = __expf(lrelu(s4.x + d4.x));
    w4.y = __expf(lrelu(s4.y + d4.y));
    w4.z = __expf(lrelu(s4.z + d4.z));
    w4.w = __expf(lrelu(s4.w + d4.w));
    int p = atomicAdd(&cursor[dst], 1);
    ssrc[p] = src;
    sw[p] = w4;
}

// gather: one wave per node, lane owns channel pair (2c,2c+1), head = lane>>4.
// Single pass (weights precomputed), unroll-by-8 for memory-level parallelism.
__global__ __launch_bounds__(256) void k_gather(
    const int* __restrict__ starts, const int* __restrict__ counts,
    const int* __restrict__ ssrc, const float* __restrict__ sw,
    const float* __restrict__ a_s, const float* __restrict__ a_d,
    const _Float16* __restrict__ h16, const float* __restrict__ bias,
    const float* __restrict__ gamma, const float* __restrict__ beta,
    float* __restrict__ out)
{
    int gid = blockIdx.x * 256 + threadIdx.x;
    int n = gid >> 6, lane = gid & 63;
    if (n >= N_NODES) return;

    const int beg = starts[n], deg = counts[n];
    const int hd = lane >> 4;
    const f16x2* h2 = (const f16x2*)h16;

    const float wSelf = __expf(lrelu(a_s[n * HEADS + hd] + a_d[n * HEADS + hd]));
    float den = wSelf;
    f16x2 hv = h2[(size_t)n * 64 + lane];
    float acc0 = (float)hv[0] * wSelf;
    float acc1 = (float)hv[1] * wSelf;

    for (int base = 0; base < deg; base += 64) {
        int nc = min(64, deg - base);
        int sv = (lane < nc) ? ssrc[beg + base + lane] : 0;
        const float* wp = sw + (size_t)(beg + base) * 4 + hd;
        int j = 0;
        for (; j + 8 <= nc; j += 8) {
            int s[8]; float w[8]; f16x2 hh[8];
#pragma unroll
            for (int k = 0; k < 8; ++k) s[k] = __shfl(sv, j + k, 64);
#pragma unroll
            for (int k = 0; k < 8; ++k) w[k] = wp[(j + k) * 4];
#pragma unroll
            for (int k = 0; k < 8; ++k) hh[k] = h2[(size_t)s[k] * 64 + lane];
#pragma unroll
            for (int k = 0; k < 8; ++k) {
                acc0 += (float)hh[k][0] * w[k];
                acc1 += (float)hh[k][1] * w[k];
                den  += w[k];
            }
        }
        for (; j < nc; ++j) {
            int s0 = __shfl(sv, j, 64);
            float w0 = wp[j * 4];
            f16x2 hx = h2[(size_t)s0 * 64 + lane];
            acc0 += (float)hx[0] * w0;
            acc1 += (float)hx[1] * w0;
            den  += w0;
        }
    }

    // ---- epilogue: normalize + bias + LayerNorm + ELU ----
    float2 bv = ((const float2*)bias)[lane];
    float2 gv = ((const float2*)gamma)[lane];
    float2 be = ((const float2*)beta)[lane];
    float v0 = acc0 / den + bv.x;
    float v1 = acc1 / den + bv.y;
    float s = v0 + v1;
#pragma unroll
    for (int off = 32; off; off >>= 1) s += __shfl_xor(s, off, 64);
    float mu = s * (1.f / 128.f);
    float d0 = v0 - mu, d1 = v1 - mu;
    float q = d0 * d0 + d1 * d1;
#pragma unroll
    for (int off = 32; off; off >>= 1) q += __shfl_xor(q, off, 64);
    float rs = rsqrtf(q * (1.f / 128.f) + LN_EPS);
    float o0 = d0 * rs * gv.x + be.x;
    float o1 = d1 * rs * gv.y + be.y;
    o0 = o0 > 0.f ? o0 : __expf(o0) - 1.f;
    o1 = o1 > 0.f ? o1 : __expf(o1) - 1.f;
    float2 ov = {o0, o1};
    ((float2*)out)[(size_t)n * 64 + lane] = ov;
}

extern "C" void kernel_launch(void* const* d_in, const int* in_sizes, int n_in,
                              void* d_out, int out_size, void* d_ws, size_t ws_size,
                              hipStream_t stream) {
    const float* x       = (const float*)d_in[0];
    const int*   ei      = (const int*)d_in[1];   // [2, E] int32: row0=src, row1=dst
    const float* W       = (const float*)d_in[2];
    const float* att_src = (const float*)d_in[3];
    const float* att_dst = (const float*)d_in[4];
    const float* bias    = (const float*)d_in[5];
    const float* gamma   = (const float*)d_in[6];
    const float* beta    = (const float*)d_in[7];
    float* out = (float*)d_out;

    char* ws = (char*)d_ws;
    // layout (16B-aligned): h16 12.8MB | a_s .8 | a_d .8 | ssrc 3.2 | sw 12.8
    //                       | counts .2 | starts .2 | cursor .2   = 31MB
    _Float16* h16    = (_Float16*)(ws);
    float*    a_s    = (float*)(ws + 12800000);
    float*    a_d    = (float*)(ws + 13600000);
    int*      ssrc   = (int*)  (ws + 14400000);
    float*    sw     = (float*)(ws + 17600000);
    int*      counts = (int*)  (ws + 30400000);
    int*      starts = (int*)  (ws + 30600000);
    int*      cursor = (int*)  (ws + 30800000);

    k1_mfma<<<(N_NODES + 63) / 64, 256, 0, stream>>>(x, W, att_src, att_dst,
                                                     h16, a_s, a_d, counts);
    k_hist<<<(N_EDGES + 255) / 256, 256, 0, stream>>>(ei, counts);
    k_scan<<<1, 1024, 0, stream>>>(counts, starts, cursor);
    k_scatter<<<(N_EDGES + 255) / 256, 256, 0, stream>>>(ei, cursor, a_s, a_d,
                                                         ssrc, (float4*)sw);
    k_gather<<<(N_NODES * 64 + 255) / 256, 256, 0, stream>>>(
        starts, counts, ssrc, sw, a_s, a_d, h16, bias, gamma, beta, out);
}

// Round 5
// 255.696 us; speedup vs baseline: 1.6576x; 1.3902x over previous
//
#include <hip/hip_runtime.h>
#include <hip/hip_bf16.h>
#include <cstdint>
#include <cstddef>

#define N_NODES 50000
#define N_EDGES 800000
#define IN_DIM 256
#define HC 128          // HEADS*OUT_DIM
#define HEADS 4
#define NEG_SLOPE 0.2f
#define LN_EPS 1e-5f

typedef _Float16 f16x8 __attribute__((ext_vector_type(8)));
typedef _Float16 f16x2 __attribute__((ext_vector_type(2)));
typedef float f32x4 __attribute__((ext_vector_type(4)));

__device__ __forceinline__ float lrelu(float x) { return x > 0.f ? x : NEG_SLOPE * x; }

// K1: h = x@W via MFMA f16 (fp32 accumulate), fused a_s/a_d dots.
// Also zeroes the histogram (saves a launch; k_hist runs after in stream order).
__global__ __launch_bounds__(256) void k1_mfma(
    const float* __restrict__ x, const float* __restrict__ W,
    const float* __restrict__ att_src, const float* __restrict__ att_dst,
    _Float16* __restrict__ h16, float* __restrict__ a_s, float* __restrict__ a_d,
    int* __restrict__ counts)
{
    __shared__ _Float16 Wt[128 * 256];   // 64 KB
    const int tid = threadIdx.x;

    int gz = blockIdx.x * 256 + tid;
    if (gz < N_NODES) counts[gz] = 0;

    for (int i = tid; i < IN_DIM * HC; i += 256) {
        int k = i >> 7, n = i & 127;           // W[k][n], coalesced read
        int g = k >> 3, j = k & 7;
        Wt[n * 256 + ((g ^ (n & 7)) << 3) + j] = (_Float16)W[i];
    }
    __syncthreads();

    const int wave = tid >> 6;
    const int lane = tid & 63;
    const int col  = lane & 15;
    const int quad = lane >> 4;
    const int m0   = blockIdx.x * 64 + wave * 16;

    const int rowA = min(m0 + col, N_NODES - 1);       // clamp tail; stores guarded
    const float* xrow = x + (size_t)rowA * IN_DIM;

    f32x4 acc[8];
#pragma unroll
    for (int nt = 0; nt < 8; ++nt) acc[nt] = (f32x4){0.f, 0.f, 0.f, 0.f};

#pragma unroll
    for (int kt = 0; kt < 8; ++kt) {
        const int k0 = kt * 32 + quad * 8;
        float4 xa = *(const float4*)(xrow + k0);
        float4 xb = *(const float4*)(xrow + k0 + 4);
        f16x8 a;
        a[0] = (_Float16)xa.x; a[1] = (_Float16)xa.y;
        a[2] = (_Float16)xa.z; a[3] = (_Float16)xa.w;
        a[4] = (_Float16)xb.x; a[5] = (_Float16)xb.y;
        a[6] = (_Float16)xb.z; a[7] = (_Float16)xb.w;
        const int g = kt * 4 + quad;
#pragma unroll
        for (int nt = 0; nt < 8; ++nt) {
            int n = nt * 16 + col;
            f16x8 b = *(const f16x8*)&Wt[n * 256 + ((g ^ (n & 7)) << 3)];
            acc[nt] = __builtin_amdgcn_mfma_f32_16x16x32_f16(a, b, acc[nt], 0, 0, 0);
        }
    }

    // epilogue: h16 store + per-(row,head) att dots
    float pS[4][4], pD[4][4];
#pragma unroll
    for (int hd = 0; hd < 4; ++hd)
#pragma unroll
        for (int r = 0; r < 4; ++r) { pS[hd][r] = 0.f; pD[hd][r] = 0.f; }

#pragma unroll
    for (int nt = 0; nt < 8; ++nt) {
        int ch = nt * 16 + col;
        float sv = att_src[ch], dv = att_dst[ch];
        int hd = nt >> 1;
#pragma unroll
        for (int r = 0; r < 4; ++r) {
            int row = m0 + quad * 4 + r;
            if (row < N_NODES) h16[(size_t)row * HC + ch] = (_Float16)acc[nt][r];
            pS[hd][r] += acc[nt][r] * sv;
            pD[hd][r] += acc[nt][r] * dv;
        }
    }
#pragma unroll
    for (int off = 1; off < 16; off <<= 1) {
#pragma unroll
        for (int hd = 0; hd < 4; ++hd)
#pragma unroll
            for (int r = 0; r < 4; ++r) {
                pS[hd][r] += __shfl_xor(pS[hd][r], off, 16);
                pD[hd][r] += __shfl_xor(pD[hd][r], off, 16);
            }
    }
    if (col == 0) {
#pragma unroll
        for (int r = 0; r < 4; ++r) {
            int row = m0 + quad * 4 + r;
            if (row < N_NODES) {
#pragma unroll
                for (int hd = 0; hd < 4; ++hd) {
                    a_s[row * HEADS + hd] = pS[hd][r];
                    a_d[row * HEADS + hd] = pD[hd][r];
                }
            }
        }
    }
}

// histogram of dst
__global__ __launch_bounds__(256) void k_hist(const int* __restrict__ ei,
                                              int* __restrict__ counts) {
    int e = blockIdx.x * 256 + threadIdx.x;
    if (e < N_EDGES) atomicAdd(&counts[ei[N_EDGES + e]], 1);
}

// hierarchical exclusive scan: 196 parallel blocks -> 1 block over partials -> add
__global__ __launch_bounds__(256) void k_scan1(const int* __restrict__ counts,
                                               int* __restrict__ starts,
                                               int* __restrict__ bsum) {
    __shared__ int s[256];
    int i = blockIdx.x * 256 + threadIdx.x;
    int v = (i < N_NODES) ? counts[i] : 0;
    s[threadIdx.x] = v; __syncthreads();
#pragma unroll
    for (int off = 1; off < 256; off <<= 1) {
        int t = (threadIdx.x >= off) ? s[threadIdx.x - off] : 0;
        __syncthreads();
        s[threadIdx.x] += t;
        __syncthreads();
    }
    if (i < N_NODES) starts[i] = s[threadIdx.x] - v;
    if (threadIdx.x == 255) bsum[blockIdx.x] = s[255];
}
__global__ __launch_bounds__(256) void k_scan2(int* __restrict__ bsum, int nb) {
    __shared__ int s[256];
    int v = (threadIdx.x < nb) ? bsum[threadIdx.x] : 0;
    s[threadIdx.x] = v; __syncthreads();
#pragma unroll
    for (int off = 1; off < 256; off <<= 1) {
        int t = (threadIdx.x >= off) ? s[threadIdx.x - off] : 0;
        __syncthreads();
        s[threadIdx.x] += t;
        __syncthreads();
    }
    if (threadIdx.x < nb) bsum[threadIdx.x] = s[threadIdx.x] - v;
}
__global__ __launch_bounds__(256) void k_scan3(int* __restrict__ starts,
                                               const int* __restrict__ bsum,
                                               int* __restrict__ cursor) {
    int i = blockIdx.x * 256 + threadIdx.x;
    if (i < N_NODES) {
        int s2 = starts[i] + bsum[blockIdx.x];
        starts[i] = s2;
        cursor[i] = s2;
    }
}

// scatter src + per-edge exp-weights (no-max softmax) into dst-sorted order.
__global__ __launch_bounds__(256) void k_scatter(
    const int* __restrict__ ei, int* __restrict__ cursor,
    const float* __restrict__ a_s, const float* __restrict__ a_d,
    int* __restrict__ ssrc, float4* __restrict__ sw)
{
    int e = blockIdx.x * 256 + threadIdx.x;
    if (e >= N_EDGES) return;
    int src = ei[e], dst = ei[N_EDGES + e];
    float4 s4 = *(const float4*)(a_s + (size_t)src * HEADS);   // L2-resident (800KB)
    float4 d4 = *(const float4*)(a_d + (size_t)dst * HEADS);
    float4 w4;
    w4.x = __expf(lrelu(s4.x + d4.x));
    w4.y = __expf(lrelu(s4.y + d4.y));
    w4.z = __expf(lrelu(s4.z + d4.z));
    w4.w = __expf(lrelu(s4.w + d4.w));
    int p = atomicAdd(&cursor[dst], 1);
    ssrc[p] = src;
    sw[p] = w4;
}

// gather: one wave per node, lane owns channel pair (2c,2c+1), head = lane>>4.
// Single pass (weights precomputed), unroll-by-8 for memory-level parallelism.
__global__ __launch_bounds__(256) void k_gather(
    const int* __restrict__ starts, const int* __restrict__ counts,
    const int* __restrict__ ssrc, const float* __restrict__ sw,
    const float* __restrict__ a_s, const float* __restrict__ a_d,
    const _Float16* __restrict__ h16, const float* __restrict__ bias,
    const float* __restrict__ gamma, const float* __restrict__ beta,
    float* __restrict__ out)
{
    int gid = blockIdx.x * 256 + threadIdx.x;
    int n = gid >> 6, lane = gid & 63;
    if (n >= N_NODES) return;

    const int beg = starts[n], deg = counts[n];
    const int hd = lane >> 4;
    const f16x2* h2 = (const f16x2*)h16;

    const float wSelf = __expf(lrelu(a_s[n * HEADS + hd] + a_d[n * HEADS + hd]));
    float den = wSelf;
    f16x2 hv = h2[(size_t)n * 64 + lane];
    float acc0 = (float)hv[0] * wSelf;
    float acc1 = (float)hv[1] * wSelf;

    for (int base = 0; base < deg; base += 64) {
        int nc = min(64, deg - base);
        int sv = (lane < nc) ? ssrc[beg + base + lane] : 0;
        const float* wp = sw + (size_t)(beg + base) * 4 + hd;
        int j = 0;
        for (; j + 8 <= nc; j += 8) {
            int s[8]; float w[8]; f16x2 hh[8];
#pragma unroll
            for (int k = 0; k < 8; ++k) s[k] = __shfl(sv, j + k, 64);
#pragma unroll
            for (int k = 0; k < 8; ++k) w[k] = wp[(j + k) * 4];
#pragma unroll
            for (int k = 0; k < 8; ++k) hh[k] = h2[(size_t)s[k] * 64 + lane];
#pragma unroll
            for (int k = 0; k < 8; ++k) {
                acc0 += (float)hh[k][0] * w[k];
                acc1 += (float)hh[k][1] * w[k];
                den  += w[k];
            }
        }
        for (; j < nc; ++j) {
            int s0 = __shfl(sv, j, 64);
            float w0 = wp[j * 4];
            f16x2 hx = h2[(size_t)s0 * 64 + lane];
            acc0 += (float)hx[0] * w0;
            acc1 += (float)hx[1] * w0;
            den  += w0;
        }
    }

    // ---- epilogue: normalize + bias + LayerNorm + ELU ----
    float2 bv = ((const float2*)bias)[lane];
    float2 gv = ((const float2*)gamma)[lane];
    float2 be = ((const float2*)beta)[lane];
    float v0 = acc0 / den + bv.x;
    float v1 = acc1 / den + bv.y;
    float s = v0 + v1;
#pragma unroll
    for (int off = 32; off; off >>= 1) s += __shfl_xor(s, off, 64);
    float mu = s * (1.f / 128.f);
    float d0 = v0 - mu, d1 = v1 - mu;
    float q = d0 * d0 + d1 * d1;
#pragma unroll
    for (int off = 32; off; off >>= 1) q += __shfl_xor(q, off, 64);
    float rs = rsqrtf(q * (1.f / 128.f) + LN_EPS);
    float o0 = d0 * rs * gv.x + be.x;
    float o1 = d1 * rs * gv.y + be.y;
    o0 = o0 > 0.f ? o0 : __expf(o0) - 1.f;
    o1 = o1 > 0.f ? o1 : __expf(o1) - 1.f;
    float2 ov = {o0, o1};
    ((float2*)out)[(size_t)n * 64 + lane] = ov;
}

extern "C" void kernel_launch(void* const* d_in, const int* in_sizes, int n_in,
                              void* d_out, int out_size, void* d_ws, size_t ws_size,
                              hipStream_t stream) {
    const float* x       = (const float*)d_in[0];
    const int*   ei      = (const int*)d_in[1];   // [2, E] int32: row0=src, row1=dst
    const float* W       = (const float*)d_in[2];
    const float* att_src = (const float*)d_in[3];
    const float* att_dst = (const float*)d_in[4];
    const float* bias    = (const float*)d_in[5];
    const float* gamma   = (const float*)d_in[6];
    const float* beta    = (const float*)d_in[7];
    float* out = (float*)d_out;

    char* ws = (char*)d_ws;
    // layout (16B-aligned): h16 12.8MB | a_s .8 | a_d .8 | ssrc 3.2 | sw 12.8
    //                       | counts .2 | starts .2 | cursor .2 | bsum 1KB
    _Float16* h16    = (_Float16*)(ws);
    float*    a_s    = (float*)(ws + 12800000);
    float*    a_d    = (float*)(ws + 13600000);
    int*      ssrc   = (int*)  (ws + 14400000);
    float*    sw     = (float*)(ws + 17600000);
    int*      counts = (int*)  (ws + 30400000);
    int*      starts = (int*)  (ws + 30600000);
    int*      cursor = (int*)  (ws + 30800000);
    int*      bsum   = (int*)  (ws + 31000000);

    const int NB = (N_NODES + 255) / 256;   // 196

    k1_mfma<<<(N_NODES + 63) / 64, 256, 0, stream>>>(x, W, att_src, att_dst,
                                                     h16, a_s, a_d, counts);
    k_hist<<<(N_EDGES + 255) / 256, 256, 0, stream>>>(ei, counts);
    k_scan1<<<NB, 256, 0, stream>>>(counts, starts, bsum);
    k_scan2<<<1, 256, 0, stream>>>(bsum, NB);
    k_scan3<<<NB, 256, 0, stream>>>(starts, bsum, cursor);
    k_scatter<<<(N_EDGES + 255) / 256, 256, 0, stream>>>(ei, cursor, a_s, a_d,
                                                         ssrc, (float4*)sw);
    k_gather<<<(N_NODES * 64 + 255) / 256, 256, 0, stream>>>(
        starts, counts, ssrc, sw, a_s, a_d, h16, bias, gamma, beta, out);
}

// Round 6
// 233.582 us; speedup vs baseline: 1.8146x; 1.0947x over previous
//
#include <hip/hip_runtime.h>
#include <hip/hip_bf16.h>
#include <cstdint>
#include <cstddef>

#define N_NODES 50000
#define N_EDGES 800000
#define IN_DIM 256
#define HC 128          // HEADS*OUT_DIM
#define HEADS 4
#define NEG_SLOPE 0.2f
#define LN_EPS 1e-5f

typedef _Float16 f16x8 __attribute__((ext_vector_type(8)));
typedef _Float16 f16x2 __attribute__((ext_vector_type(2)));
typedef float f32x4 __attribute__((ext_vector_type(4)));

__device__ __forceinline__ float lrelu(float x) { return x > 0.f ? x : NEG_SLOPE * x; }
__device__ __forceinline__ unsigned pack_h2(float a, float b) {
    f16x2 h; h[0] = (_Float16)a; h[1] = (_Float16)b;
    return *(unsigned*)&h;
}

// K1: h = x@W via MFMA f16 (fp32 accumulate), fused a_s/a_d dots.
// Also zeroes the histogram (k_hist runs after in stream order).
__global__ __launch_bounds__(256) void k1_mfma(
    const float* __restrict__ x, const float* __restrict__ W,
    const float* __restrict__ att_src, const float* __restrict__ att_dst,
    _Float16* __restrict__ h16, float* __restrict__ a_s, float* __restrict__ a_d,
    int* __restrict__ counts)
{
    __shared__ _Float16 Wt[128 * 256];   // 64 KB
    const int tid = threadIdx.x;

    int gz = blockIdx.x * 256 + tid;
    if (gz < N_NODES) counts[gz] = 0;

    for (int i = tid; i < IN_DIM * HC; i += 256) {
        int k = i >> 7, n = i & 127;           // W[k][n], coalesced read
        int g = k >> 3, j = k & 7;
        Wt[n * 256 + ((g ^ (n & 7)) << 3) + j] = (_Float16)W[i];
    }
    __syncthreads();

    const int wave = tid >> 6;
    const int lane = tid & 63;
    const int col  = lane & 15;
    const int quad = lane >> 4;
    const int m0   = blockIdx.x * 64 + wave * 16;

    const int rowA = min(m0 + col, N_NODES - 1);       // clamp tail; stores guarded
    const float* xrow = x + (size_t)rowA * IN_DIM;

    f32x4 acc[8];
#pragma unroll
    for (int nt = 0; nt < 8; ++nt) acc[nt] = (f32x4){0.f, 0.f, 0.f, 0.f};

#pragma unroll
    for (int kt = 0; kt < 8; ++kt) {
        const int k0 = kt * 32 + quad * 8;
        float4 xa = *(const float4*)(xrow + k0);
        float4 xb = *(const float4*)(xrow + k0 + 4);
        f16x8 a;
        a[0] = (_Float16)xa.x; a[1] = (_Float16)xa.y;
        a[2] = (_Float16)xa.z; a[3] = (_Float16)xa.w;
        a[4] = (_Float16)xb.x; a[5] = (_Float16)xb.y;
        a[6] = (_Float16)xb.z; a[7] = (_Float16)xb.w;
        const int g = kt * 4 + quad;
#pragma unroll
        for (int nt = 0; nt < 8; ++nt) {
            int n = nt * 16 + col;
            f16x8 b = *(const f16x8*)&Wt[n * 256 + ((g ^ (n & 7)) << 3)];
            acc[nt] = __builtin_amdgcn_mfma_f32_16x16x32_f16(a, b, acc[nt], 0, 0, 0);
        }
    }

    // epilogue: h16 store + per-(row,head) att dots
    float pS[4][4], pD[4][4];
#pragma unroll
    for (int hd = 0; hd < 4; ++hd)
#pragma unroll
        for (int r = 0; r < 4; ++r) { pS[hd][r] = 0.f; pD[hd][r] = 0.f; }

#pragma unroll
    for (int nt = 0; nt < 8; ++nt) {
        int ch = nt * 16 + col;
        float sv = att_src[ch], dv = att_dst[ch];
        int hd = nt >> 1;
#pragma unroll
        for (int r = 0; r < 4; ++r) {
            int row = m0 + quad * 4 + r;
            if (row < N_NODES) h16[(size_t)row * HC + ch] = (_Float16)acc[nt][r];
            pS[hd][r] += acc[nt][r] * sv;
            pD[hd][r] += acc[nt][r] * dv;
        }
    }
#pragma unroll
    for (int off = 1; off < 16; off <<= 1) {
#pragma unroll
        for (int hd = 0; hd < 4; ++hd)
#pragma unroll
            for (int r = 0; r < 4; ++r) {
                pS[hd][r] += __shfl_xor(pS[hd][r], off, 16);
                pD[hd][r] += __shfl_xor(pD[hd][r], off, 16);
            }
    }
    if (col == 0) {
#pragma unroll
        for (int r = 0; r < 4; ++r) {
            int row = m0 + quad * 4 + r;
            if (row < N_NODES) {
#pragma unroll
                for (int hd = 0; hd < 4; ++hd) {
                    a_s[row * HEADS + hd] = pS[hd][r];
                    a_d[row * HEADS + hd] = pD[hd][r];
                }
            }
        }
    }
}

// histogram of dst; keep the atomic's return as the edge's rank within its dst
__global__ __launch_bounds__(256) void k_hist(const int* __restrict__ ei,
                                              int* __restrict__ counts,
                                              int* __restrict__ rank) {
    int e = blockIdx.x * 256 + threadIdx.x;
    if (e < N_EDGES) rank[e] = atomicAdd(&counts[ei[N_EDGES + e]], 1);
}

// hierarchical exclusive scan: 196 parallel blocks -> 1 block over partials -> add
__global__ __launch_bounds__(256) void k_scan1(const int* __restrict__ counts,
                                               int* __restrict__ starts,
                                               int* __restrict__ bsum) {
    __shared__ int s[256];
    int i = blockIdx.x * 256 + threadIdx.x;
    int v = (i < N_NODES) ? counts[i] : 0;
    s[threadIdx.x] = v; __syncthreads();
#pragma unroll
    for (int off = 1; off < 256; off <<= 1) {
        int t = (threadIdx.x >= off) ? s[threadIdx.x - off] : 0;
        __syncthreads();
        s[threadIdx.x] += t;
        __syncthreads();
    }
    if (i < N_NODES) starts[i] = s[threadIdx.x] - v;
    if (threadIdx.x == 255) bsum[blockIdx.x] = s[255];
}
__global__ __launch_bounds__(256) void k_scan2(int* __restrict__ bsum, int nb) {
    __shared__ int s[256];
    int v = (threadIdx.x < nb) ? bsum[threadIdx.x] : 0;
    s[threadIdx.x] = v; __syncthreads();
#pragma unroll
    for (int off = 1; off < 256; off <<= 1) {
        int t = (threadIdx.x >= off) ? s[threadIdx.x - off] : 0;
        __syncthreads();
        s[threadIdx.x] += t;
        __syncthreads();
    }
    if (threadIdx.x < nb) bsum[threadIdx.x] = s[threadIdx.x] - v;
}
__global__ __launch_bounds__(256) void k_scan3(int* __restrict__ starts,
                                               const int* __restrict__ bsum) {
    int i = blockIdx.x * 256 + threadIdx.x;
    if (i < N_NODES) starts[i] += bsum[blockIdx.x];
}

// scatter: NO atomics (p = starts[dst] + rank[e]); one 16B record per edge
// {src:int, w0..w3:f16} -> single random cacheline touched per edge.
__global__ __launch_bounds__(256) void k_scatter(
    const int* __restrict__ ei, const int* __restrict__ starts,
    const int* __restrict__ rank, const float* __restrict__ a_s,
    const float* __restrict__ a_d, int4* __restrict__ rec)
{
    int e = blockIdx.x * 256 + threadIdx.x;
    if (e >= N_EDGES) return;
    int src = ei[e], dst = ei[N_EDGES + e];
    float4 s4 = *(const float4*)(a_s + (size_t)src * HEADS);   // L2-resident (800KB)
    float4 d4 = *(const float4*)(a_d + (size_t)dst * HEADS);
    float w0 = __expf(lrelu(s4.x + d4.x));
    float w1 = __expf(lrelu(s4.y + d4.y));
    float w2 = __expf(lrelu(s4.z + d4.z));
    float w3 = __expf(lrelu(s4.w + d4.w));
    int p = starts[dst] + rank[e];
    int4 r;
    r.x = src;
    r.y = (int)pack_h2(w0, w1);
    r.z = (int)pack_h2(w2, w3);
    r.w = 0;
    rec[p] = r;
}

// gather: one wave per node, lane owns channel pair (2c,2c+1), head = lane>>4.
// Records carry src + f16 weights; weight reaches the lane via shfl+select.
__global__ __launch_bounds__(256) void k_gather(
    const int* __restrict__ starts, const int* __restrict__ counts,
    const int4* __restrict__ rec, const float* __restrict__ a_s,
    const float* __restrict__ a_d, const _Float16* __restrict__ h16,
    const float* __restrict__ bias, const float* __restrict__ gamma,
    const float* __restrict__ beta, float* __restrict__ out)
{
    int gid = blockIdx.x * 256 + threadIdx.x;
    int n = gid >> 6, lane = gid & 63;
    if (n >= N_NODES) return;

    const int beg = starts[n], deg = counts[n];
    const int hd = lane >> 4;
    const bool hiPair = hd >= 2;     // pick w23 vs w01
    const int  sub    = hd & 1;      // low/high half within the pair
    const f16x2* h2 = (const f16x2*)h16;

    const float wSelf = __expf(lrelu(a_s[n * HEADS + hd] + a_d[n * HEADS + hd]));
    float den = wSelf;
    f16x2 hv = h2[(size_t)n * 64 + lane];
    float acc0 = (float)hv[0] * wSelf;
    float acc1 = (float)hv[1] * wSelf;

    for (int base = 0; base < deg; base += 64) {
        int nc = min(64, deg - base);
        int4 rv = (lane < nc) ? rec[beg + base + lane] : (int4){0, 0, 0, 0};
        int sv = rv.x, wlo = rv.y, whi = rv.z;
        int j = 0;
        for (; j + 8 <= nc; j += 8) {
            int s[8]; float w[8]; f16x2 hh[8];
#pragma unroll
            for (int k = 0; k < 8; ++k) {
                s[k] = __shfl(sv, j + k, 64);
                int ua = __shfl(wlo, j + k, 64);
                int ub = __shfl(whi, j + k, 64);
                int u = hiPair ? ub : ua;
                f16x2 wp = *(f16x2*)&u;
                w[k] = (float)wp[sub];
            }
#pragma unroll
            for (int k = 0; k < 8; ++k) hh[k] = h2[(size_t)s[k] * 64 + lane];
#pragma unroll
            for (int k = 0; k < 8; ++k) {
                acc0 += (float)hh[k][0] * w[k];
                acc1 += (float)hh[k][1] * w[k];
                den  += w[k];
            }
        }
        for (; j < nc; ++j) {
            int s0 = __shfl(sv, j, 64);
            int ua = __shfl(wlo, j, 64);
            int ub = __shfl(whi, j, 64);
            int u = hiPair ? ub : ua;
            f16x2 wp = *(f16x2*)&u;
            float w0 = (float)wp[sub];
            f16x2 hx = h2[(size_t)s0 * 64 + lane];
            acc0 += (float)hx[0] * w0;
            acc1 += (float)hx[1] * w0;
            den  += w0;
        }
    }

    // ---- epilogue: normalize + bias + LayerNorm + ELU ----
    float2 bv = ((const float2*)bias)[lane];
    float2 gv = ((const float2*)gamma)[lane];
    float2 be = ((const float2*)beta)[lane];
    float v0 = acc0 / den + bv.x;
    float v1 = acc1 / den + bv.y;
    float s = v0 + v1;
#pragma unroll
    for (int off = 32; off; off >>= 1) s += __shfl_xor(s, off, 64);
    float mu = s * (1.f / 128.f);
    float d0 = v0 - mu, d1 = v1 - mu;
    float q = d0 * d0 + d1 * d1;
#pragma unroll
    for (int off = 32; off; off >>= 1) q += __shfl_xor(q, off, 64);
    float rs = rsqrtf(q * (1.f / 128.f) + LN_EPS);
    float o0 = d0 * rs * gv.x + be.x;
    float o1 = d1 * rs * gv.y + be.y;
    o0 = o0 > 0.f ? o0 : __expf(o0) - 1.f;
    o1 = o1 > 0.f ? o1 : __expf(o1) - 1.f;
    float2 ov = {o0, o1};
    ((float2*)out)[(size_t)n * 64 + lane] = ov;
}

extern "C" void kernel_launch(void* const* d_in, const int* in_sizes, int n_in,
                              void* d_out, int out_size, void* d_ws, size_t ws_size,
                              hipStream_t stream) {
    const float* x       = (const float*)d_in[0];
    const int*   ei      = (const int*)d_in[1];   // [2, E] int32: row0=src, row1=dst
    const float* W       = (const float*)d_in[2];
    const float* att_src = (const float*)d_in[3];
    const float* att_dst = (const float*)d_in[4];
    const float* bias    = (const float*)d_in[5];
    const float* gamma   = (const float*)d_in[6];
    const float* beta    = (const float*)d_in[7];
    float* out = (float*)d_out;

    char* ws = (char*)d_ws;
    // layout (16B-aligned): h16 12.8MB | a_s .8 | a_d .8 | rec 12.8 | rank 3.2
    //                       | counts .2 | starts .2 | bsum 1KB   = 30.8MB
    _Float16* h16    = (_Float16*)(ws);
    float*    a_s    = (float*)(ws + 12800000);
    float*    a_d    = (float*)(ws + 13600000);
    int4*     rec    = (int4*) (ws + 14400000);
    int*      rank   = (int*)  (ws + 27200000);
    int*      counts = (int*)  (ws + 30400000);
    int*      starts = (int*)  (ws + 30600000);
    int*      bsum   = (int*)  (ws + 30800000);

    const int NB = (N_NODES + 255) / 256;   // 196

    k1_mfma<<<(N_NODES + 63) / 64, 256, 0, stream>>>(x, W, att_src, att_dst,
                                                     h16, a_s, a_d, counts);
    k_hist<<<(N_EDGES + 255) / 256, 256, 0, stream>>>(ei, counts, rank);
    k_scan1<<<NB, 256, 0, stream>>>(counts, starts, bsum);
    k_scan2<<<1, 256, 0, stream>>>(bsum, NB);
    k_scan3<<<NB, 256, 0, stream>>>(starts, bsum);
    k_scatter<<<(N_EDGES + 255) / 256, 256, 0, stream>>>(ei, starts, rank,
                                                         a_s, a_d, rec);
    k_gather<<<(N_NODES * 64 + 255) / 256, 256, 0, stream>>>(
        starts, counts, rec, a_s, a_d, h16, bias, gamma, beta, out);
}

// Round 7
// 224.814 us; speedup vs baseline: 1.8853x; 1.0390x over previous
//
#include <hip/hip_runtime.h>
#include <hip/hip_bf16.h>
#include <cstdint>
#include <cstddef>

#define N_NODES 50000
#define N_EDGES 800000
#define IN_DIM 256
#define HC 128          // HEADS*OUT_DIM
#define HEADS 4
#define NEG_SLOPE 0.2f
#define LN_EPS 1e-5f

typedef _Float16 f16x8 __attribute__((ext_vector_type(8)));
typedef _Float16 f16x2 __attribute__((ext_vector_type(2)));
typedef float f32x4 __attribute__((ext_vector_type(4)));

__device__ __forceinline__ float lrelu(float x) { return x > 0.f ? x : NEG_SLOPE * x; }
__device__ __forceinline__ unsigned pack_h2(float a, float b) {
    f16x2 h; h[0] = (_Float16)a; h[1] = (_Float16)b;
    return *(unsigned*)&h;
}

// K0: build fragment-ordered f16 W + zero the histogram.
// W16 chunk c (16B, 8 halves): c = ((kt*8+nt)*64 + quad*16 + col),
// element j = W[(kt*32+quad*8+j)*HC + nt*16+col]. A wave reading frag (kt,nt)
// then touches 64 contiguous 16B chunks -> conflict-free ds_read_b128.
__global__ __launch_bounds__(256) void k0_prep(const float* __restrict__ W,
                                               _Float16* __restrict__ W16,
                                               int* __restrict__ counts) {
    int b = blockIdx.x;
    if (b < 16) {
        int c = b * 256 + threadIdx.x;         // 0..4095
        int col = c & 15, quad = (c >> 4) & 3, nt = (c >> 6) & 7, kt = c >> 9;
        int n = nt * 16 + col;
        f16x8 v;
#pragma unroll
        for (int j = 0; j < 8; ++j) {
            int k = kt * 32 + quad * 8 + j;
            v[j] = (_Float16)W[k * HC + n];
        }
        *(f16x8*)(W16 + (size_t)c * 8) = v;
    } else {
        int i = (b - 16) * 256 + threadIdx.x;
        if (i < N_NODES) counts[i] = 0;
    }
}

// K1: h = x@W via MFMA f16, W16 staged conflict-free, x prefetched per kt.
__global__ __launch_bounds__(256) void k1_mfma(
    const float* __restrict__ x, const _Float16* __restrict__ W16,
    const float* __restrict__ att_src, const float* __restrict__ att_dst,
    _Float16* __restrict__ h16, float* __restrict__ a_s, float* __restrict__ a_d)
{
    __shared__ _Float16 Wlds[32768];   // 64 KB, fragment-ordered
    const int tid = threadIdx.x;

    {   // stage: 16 iters x (256 lanes x 16B), lane-contiguous -> no conflicts
        const uint4* g4 = (const uint4*)W16;
        uint4* s4 = (uint4*)Wlds;
#pragma unroll
        for (int it = 0; it < 16; ++it) s4[it * 256 + tid] = g4[it * 256 + tid];
    }
    __syncthreads();

    const int wave = tid >> 6;
    const int lane = tid & 63;
    const int col  = lane & 15;
    const int quad = lane >> 4;
    const int m0   = blockIdx.x * 64 + wave * 16;

    const int rowA = min(m0 + col, N_NODES - 1);       // clamp tail; stores guarded
    const float* xrow = x + (size_t)rowA * IN_DIM + quad * 8;

    f32x4 acc[8];
#pragma unroll
    for (int nt = 0; nt < 8; ++nt) acc[nt] = (f32x4){0.f, 0.f, 0.f, 0.f};

    float4 xa = *(const float4*)(xrow);
    float4 xb = *(const float4*)(xrow + 4);
#pragma unroll
    for (int kt = 0; kt < 8; ++kt) {
        float4 na, nb;
        if (kt < 7) {                       // prefetch next k-block of x
            na = *(const float4*)(xrow + (kt + 1) * 32);
            nb = *(const float4*)(xrow + (kt + 1) * 32 + 4);
        }
        f16x8 a;
        a[0] = (_Float16)xa.x; a[1] = (_Float16)xa.y;
        a[2] = (_Float16)xa.z; a[3] = (_Float16)xa.w;
        a[4] = (_Float16)xb.x; a[5] = (_Float16)xb.y;
        a[6] = (_Float16)xb.z; a[7] = (_Float16)xb.w;
#pragma unroll
        for (int nt = 0; nt < 8; ++nt) {
            f16x8 b = *(const f16x8*)&Wlds[((kt * 8 + nt) * 64 + quad * 16 + col) * 8];
            acc[nt] = __builtin_amdgcn_mfma_f32_16x16x32_f16(a, b, acc[nt], 0, 0, 0);
        }
        xa = na; xb = nb;
    }

    // epilogue: h16 store + per-(row,head) att dots
    float pS[4][4], pD[4][4];
#pragma unroll
    for (int hd = 0; hd < 4; ++hd)
#pragma unroll
        for (int r = 0; r < 4; ++r) { pS[hd][r] = 0.f; pD[hd][r] = 0.f; }

#pragma unroll
    for (int nt = 0; nt < 8; ++nt) {
        int ch = nt * 16 + col;
        float sv = att_src[ch], dv = att_dst[ch];
        int hd = nt >> 1;
#pragma unroll
        for (int r = 0; r < 4; ++r) {
            int row = m0 + quad * 4 + r;
            if (row < N_NODES) h16[(size_t)row * HC + ch] = (_Float16)acc[nt][r];
            pS[hd][r] += acc[nt][r] * sv;
            pD[hd][r] += acc[nt][r] * dv;
        }
    }
#pragma unroll
    for (int off = 1; off < 16; off <<= 1) {
#pragma unroll
        for (int hd = 0; hd < 4; ++hd)
#pragma unroll
            for (int r = 0; r < 4; ++r) {
                pS[hd][r] += __shfl_xor(pS[hd][r], off, 16);
                pD[hd][r] += __shfl_xor(pD[hd][r], off, 16);
            }
    }
    if (col == 0) {
#pragma unroll
        for (int r = 0; r < 4; ++r) {
            int row = m0 + quad * 4 + r;
            if (row < N_NODES) {
#pragma unroll
                for (int hd = 0; hd < 4; ++hd) {
                    a_s[row * HEADS + hd] = pS[hd][r];
                    a_d[row * HEADS + hd] = pD[hd][r];
                }
            }
        }
    }
}

// histogram of dst; keep the atomic's return as the edge's rank within its dst
__global__ __launch_bounds__(256) void k_hist(const int* __restrict__ ei,
                                              int* __restrict__ counts,
                                              int* __restrict__ rank) {
    int e = blockIdx.x * 256 + threadIdx.x;
    if (e < N_EDGES) rank[e] = atomicAdd(&counts[ei[N_EDGES + e]], 1);
}

// hierarchical scan: block-local exclusive + block sums; bsum scanned by scan2;
// consumers add bsum[i>>8] themselves (no scan3 pass).
__global__ __launch_bounds__(256) void k_scan1(const int* __restrict__ counts,
                                               int* __restrict__ starts,
                                               int* __restrict__ bsum) {
    __shared__ int s[256];
    int i = blockIdx.x * 256 + threadIdx.x;
    int v = (i < N_NODES) ? counts[i] : 0;
    s[threadIdx.x] = v; __syncthreads();
#pragma unroll
    for (int off = 1; off < 256; off <<= 1) {
        int t = (threadIdx.x >= off) ? s[threadIdx.x - off] : 0;
        __syncthreads();
        s[threadIdx.x] += t;
        __syncthreads();
    }
    if (i < N_NODES) starts[i] = s[threadIdx.x] - v;
    if (threadIdx.x == 255) bsum[blockIdx.x] = s[255];
}
__global__ __launch_bounds__(256) void k_scan2(int* __restrict__ bsum, int nb) {
    __shared__ int s[256];
    int v = (threadIdx.x < nb) ? bsum[threadIdx.x] : 0;
    s[threadIdx.x] = v; __syncthreads();
#pragma unroll
    for (int off = 1; off < 256; off <<= 1) {
        int t = (threadIdx.x >= off) ? s[threadIdx.x - off] : 0;
        __syncthreads();
        s[threadIdx.x] += t;
        __syncthreads();
    }
    if (threadIdx.x < nb) bsum[threadIdx.x] = s[threadIdx.x] - v;
}

// scatter: NO atomics (p = starts[dst]+bsum[dst>>8]+rank[e]); one 16B record
// {src:int, w0..w3:f16} per edge -> single random cacheline per edge.
__global__ __launch_bounds__(256) void k_scatter(
    const int* __restrict__ ei, const int* __restrict__ starts,
    const int* __restrict__ bsum, const int* __restrict__ rank,
    const float* __restrict__ a_s, const float* __restrict__ a_d,
    int4* __restrict__ rec)
{
    int e = blockIdx.x * 256 + threadIdx.x;
    if (e >= N_EDGES) return;
    int src = ei[e], dst = ei[N_EDGES + e];
    float4 s4 = *(const float4*)(a_s + (size_t)src * HEADS);   // L2-resident (800KB)
    float4 d4 = *(const float4*)(a_d + (size_t)dst * HEADS);
    float w0 = __expf(lrelu(s4.x + d4.x));
    float w1 = __expf(lrelu(s4.y + d4.y));
    float w2 = __expf(lrelu(s4.z + d4.z));
    float w3 = __expf(lrelu(s4.w + d4.w));
    int p = starts[dst] + bsum[dst >> 8] + rank[e];
    int4 r;
    r.x = src;
    r.y = (int)pack_h2(w0, w1);
    r.z = (int)pack_h2(w2, w3);
    r.w = 0;
    rec[p] = r;
}

// gather: one wave per node, lane owns channel pair (2c,2c+1), head = lane>>4.
__global__ __launch_bounds__(256) void k_gather(
    const int* __restrict__ starts, const int* __restrict__ bsum,
    const int* __restrict__ counts, const int4* __restrict__ rec,
    const float* __restrict__ a_s, const float* __restrict__ a_d,
    const _Float16* __restrict__ h16, const float* __restrict__ bias,
    const float* __restrict__ gamma, const float* __restrict__ beta,
    float* __restrict__ out)
{
    int gid = blockIdx.x * 256 + threadIdx.x;
    int n = gid >> 6, lane = gid & 63;
    if (n >= N_NODES) return;

    const int beg = starts[n] + bsum[n >> 8];
    const int deg = counts[n];
    const int hd = lane >> 4;
    const bool hiPair = hd >= 2;
    const int  sub    = hd & 1;
    const f16x2* h2 = (const f16x2*)h16;

    const float wSelf = __expf(lrelu(a_s[n * HEADS + hd] + a_d[n * HEADS + hd]));
    float den = wSelf;
    f16x2 hv = h2[(size_t)n * 64 + lane];
    float acc0 = (float)hv[0] * wSelf;
    float acc1 = (float)hv[1] * wSelf;

    for (int base = 0; base < deg; base += 64) {
        int nc = min(64, deg - base);
        int4 rv = (lane < nc) ? rec[beg + base + lane] : (int4){0, 0, 0, 0};
        int sv = rv.x, wlo = rv.y, whi = rv.z;
        int j = 0;
        for (; j + 8 <= nc; j += 8) {
            int s[8]; float w[8]; f16x2 hh[8];
#pragma unroll
            for (int k = 0; k < 8; ++k) {
                s[k] = __shfl(sv, j + k, 64);
                int ua = __shfl(wlo, j + k, 64);
                int ub = __shfl(whi, j + k, 64);
                int u = hiPair ? ub : ua;
                f16x2 wp = *(f16x2*)&u;
                w[k] = (float)wp[sub];
            }
#pragma unroll
            for (int k = 0; k < 8; ++k) hh[k] = h2[(size_t)s[k] * 64 + lane];
#pragma unroll
            for (int k = 0; k < 8; ++k) {
                acc0 += (float)hh[k][0] * w[k];
                acc1 += (float)hh[k][1] * w[k];
                den  += w[k];
            }
        }
        for (; j < nc; ++j) {
            int s0 = __shfl(sv, j, 64);
            int ua = __shfl(wlo, j, 64);
            int ub = __shfl(whi, j, 64);
            int u = hiPair ? ub : ua;
            f16x2 wp = *(f16x2*)&u;
            float w0 = (float)wp[sub];
            f16x2 hx = h2[(size_t)s0 * 64 + lane];
            acc0 += (float)hx[0] * w0;
            acc1 += (float)hx[1] * w0;
            den  += w0;
        }
    }

    // ---- epilogue: normalize + bias + LayerNorm + ELU ----
    float2 bv = ((const float2*)bias)[lane];
    float2 gv = ((const float2*)gamma)[lane];
    float2 be = ((const float2*)beta)[lane];
    float v0 = acc0 / den + bv.x;
    float v1 = acc1 / den + bv.y;
    float s = v0 + v1;
#pragma unroll
    for (int off = 32; off; off >>= 1) s += __shfl_xor(s, off, 64);
    float mu = s * (1.f / 128.f);
    float d0 = v0 - mu, d1 = v1 - mu;
    float q = d0 * d0 + d1 * d1;
#pragma unroll
    for (int off = 32; off; off >>= 1) q += __shfl_xor(q, off, 64);
    float rs = rsqrtf(q * (1.f / 128.f) + LN_EPS);
    float o0 = d0 * rs * gv.x + be.x;
    float o1 = d1 * rs * gv.y + be.y;
    o0 = o0 > 0.f ? o0 : __expf(o0) - 1.f;
    o1 = o1 > 0.f ? o1 : __expf(o1) - 1.f;
    float2 ov = {o0, o1};
    ((float2*)out)[(size_t)n * 64 + lane] = ov;
}

extern "C" void kernel_launch(void* const* d_in, const int* in_sizes, int n_in,
                              void* d_out, int out_size, void* d_ws, size_t ws_size,
                              hipStream_t stream) {
    const float* x       = (const float*)d_in[0];
    const int*   ei      = (const int*)d_in[1];   // [2, E] int32: row0=src, row1=dst
    const float* W       = (const float*)d_in[2];
    const float* att_src = (const float*)d_in[3];
    const float* att_dst = (const float*)d_in[4];
    const float* bias    = (const float*)d_in[5];
    const float* gamma   = (const float*)d_in[6];
    const float* beta    = (const float*)d_in[7];
    float* out = (float*)d_out;

    char* ws = (char*)d_ws;
    // layout (16B-aligned): h16 12.8MB | a_s .8 | a_d .8 | rec 12.8 | rank 3.2
    //                       | counts .2 | starts .2 | bsum 1KB | W16 64KB
    _Float16* h16    = (_Float16*)(ws);
    float*    a_s    = (float*)(ws + 12800000);
    float*    a_d    = (float*)(ws + 13600000);
    int4*     rec    = (int4*) (ws + 14400000);
    int*      rank   = (int*)  (ws + 27200000);
    int*      counts = (int*)  (ws + 30400000);
    int*      starts = (int*)  (ws + 30600000);
    int*      bsum   = (int*)  (ws + 30800000);
    _Float16* W16    = (_Float16*)(ws + 30810240);

    const int NB = (N_NODES + 255) / 256;   // 196

    k0_prep<<<16 + NB, 256, 0, stream>>>(W, W16, counts);
    k1_mfma<<<(N_NODES + 63) / 64, 256, 0, stream>>>(x, W16, att_src, att_dst,
                                                     h16, a_s, a_d);
    k_hist<<<(N_EDGES + 255) / 256, 256, 0, stream>>>(ei, counts, rank);
    k_scan1<<<NB, 256, 0, stream>>>(counts, starts, bsum);
    k_scan2<<<1, 256, 0, stream>>>(bsum, NB);
    k_scatter<<<(N_EDGES + 255) / 256, 256, 0, stream>>>(ei, starts, bsum, rank,
                                                         a_s, a_d, rec);
    k_gather<<<(N_NODES * 64 + 255) / 256, 256, 0, stream>>>(
        starts, bsum, counts, rec, a_s, a_d, h16, bias, gamma, beta, out);
}

// Round 8
// 223.159 us; speedup vs baseline: 1.8993x; 1.0074x over previous
//
#include <hip/hip_runtime.h>
#include <hip/hip_bf16.h>
#include <cstdint>
#include <cstddef>

#define N_NODES 50000
#define N_EDGES 800000
#define IN_DIM 256
#define HC 128          // HEADS*OUT_DIM
#define HEADS 4
#define NEG_SLOPE 0.2f
#define LN_EPS 1e-5f

typedef _Float16 f16x8 __attribute__((ext_vector_type(8)));
typedef _Float16 f16x2 __attribute__((ext_vector_type(2)));
typedef float f32x4 __attribute__((ext_vector_type(4)));

__device__ __forceinline__ float lrelu(float x) { return x > 0.f ? x : NEG_SLOPE * x; }
__device__ __forceinline__ unsigned pack_h2(float a, float b) {
    f16x2 h; h[0] = (_Float16)a; h[1] = (_Float16)b;
    return *(unsigned*)&h;
}

// K0: build fragment-ordered f16 W + zero the histogram.
// W16 chunk c (16B, 8 halves): c = ((kt*8+nt)*64 + quad*16 + col),
// element j = W[(kt*32+quad*8+j)*HC + nt*16+col].
__global__ __launch_bounds__(256) void k0_prep(const float* __restrict__ W,
                                               _Float16* __restrict__ W16,
                                               int* __restrict__ counts) {
    int b = blockIdx.x;
    if (b < 16) {
        int c = b * 256 + threadIdx.x;         // 0..4095
        int col = c & 15, quad = (c >> 4) & 3, nt = (c >> 6) & 7, kt = c >> 9;
        int n = nt * 16 + col;
        f16x8 v;
#pragma unroll
        for (int j = 0; j < 8; ++j) {
            int k = kt * 32 + quad * 8 + j;
            v[j] = (_Float16)W[k * HC + n];
        }
        *(f16x8*)(W16 + (size_t)c * 8) = v;
    } else {
        int i = (b - 16) * 256 + threadIdx.x;
        if (i < N_NODES) counts[i] = 0;
    }
}

// K1: h = x@W via MFMA f16. B-fragments read straight from L2-resident W16
// (64 KB, every wave reads the same lines) — no LDS, no __syncthreads,
// occupancy limited only by VGPRs.
__global__ __launch_bounds__(256) void k1_mfma(
    const float* __restrict__ x, const _Float16* __restrict__ W16,
    const float* __restrict__ att_src, const float* __restrict__ att_dst,
    _Float16* __restrict__ h16, float* __restrict__ a_s, float* __restrict__ a_d)
{
    const int tid  = threadIdx.x;
    const int wave = tid >> 6;
    const int lane = tid & 63;
    const int col  = lane & 15;
    const int quad = lane >> 4;
    const int m0   = blockIdx.x * 64 + wave * 16;

    const int rowA = min(m0 + col, N_NODES - 1);       // clamp tail; stores guarded
    const float* xrow = x + (size_t)rowA * IN_DIM + quad * 8;
    const f16x8* Wf = (const f16x8*)W16;               // fragment-ordered chunks

    f32x4 acc[8];
#pragma unroll
    for (int nt = 0; nt < 8; ++nt) acc[nt] = (f32x4){0.f, 0.f, 0.f, 0.f};

    float4 xa = *(const float4*)(xrow);
    float4 xb = *(const float4*)(xrow + 4);
#pragma unroll
    for (int kt = 0; kt < 8; ++kt) {
        float4 na, nb;
        if (kt < 7) {                       // prefetch next k-block of x
            na = *(const float4*)(xrow + (kt + 1) * 32);
            nb = *(const float4*)(xrow + (kt + 1) * 32 + 4);
        }
        f16x8 a;
        a[0] = (_Float16)xa.x; a[1] = (_Float16)xa.y;
        a[2] = (_Float16)xa.z; a[3] = (_Float16)xa.w;
        a[4] = (_Float16)xb.x; a[5] = (_Float16)xb.y;
        a[6] = (_Float16)xb.z; a[7] = (_Float16)xb.w;
#pragma unroll
        for (int nt = 0; nt < 8; ++nt) {
            f16x8 b = Wf[(kt * 8 + nt) * 64 + quad * 16 + col];   // L2-hit, coalesced
            acc[nt] = __builtin_amdgcn_mfma_f32_16x16x32_f16(a, b, acc[nt], 0, 0, 0);
        }
        xa = na; xb = nb;
    }

    // epilogue: h16 store + per-(row,head) att dots
    float pS[4][4], pD[4][4];
#pragma unroll
    for (int hd = 0; hd < 4; ++hd)
#pragma unroll
        for (int r = 0; r < 4; ++r) { pS[hd][r] = 0.f; pD[hd][r] = 0.f; }

#pragma unroll
    for (int nt = 0; nt < 8; ++nt) {
        int ch = nt * 16 + col;
        float sv = att_src[ch], dv = att_dst[ch];
        int hd = nt >> 1;
#pragma unroll
        for (int r = 0; r < 4; ++r) {
            int row = m0 + quad * 4 + r;
            if (row < N_NODES) h16[(size_t)row * HC + ch] = (_Float16)acc[nt][r];
            pS[hd][r] += acc[nt][r] * sv;
            pD[hd][r] += acc[nt][r] * dv;
        }
    }
#pragma unroll
    for (int off = 1; off < 16; off <<= 1) {
#pragma unroll
        for (int hd = 0; hd < 4; ++hd)
#pragma unroll
            for (int r = 0; r < 4; ++r) {
                pS[hd][r] += __shfl_xor(pS[hd][r], off, 16);
                pD[hd][r] += __shfl_xor(pD[hd][r], off, 16);
            }
    }
    if (col == 0) {
#pragma unroll
        for (int r = 0; r < 4; ++r) {
            int row = m0 + quad * 4 + r;
            if (row < N_NODES) {
#pragma unroll
                for (int hd = 0; hd < 4; ++hd) {
                    a_s[row * HEADS + hd] = pS[hd][r];
                    a_d[row * HEADS + hd] = pD[hd][r];
                }
            }
        }
    }
}

// histogram of dst; keep the atomic's return as the edge's rank within its dst
__global__ __launch_bounds__(256) void k_hist(const int* __restrict__ ei,
                                              int* __restrict__ counts,
                                              int* __restrict__ rank) {
    int e = blockIdx.x * 256 + threadIdx.x;
    if (e < N_EDGES) rank[e] = atomicAdd(&counts[ei[N_EDGES + e]], 1);
}

// hierarchical scan: block-local exclusive + block sums; consumers add bsum[i>>8]
__global__ __launch_bounds__(256) void k_scan1(const int* __restrict__ counts,
                                               int* __restrict__ starts,
                                               int* __restrict__ bsum) {
    __shared__ int s[256];
    int i = blockIdx.x * 256 + threadIdx.x;
    int v = (i < N_NODES) ? counts[i] : 0;
    s[threadIdx.x] = v; __syncthreads();
#pragma unroll
    for (int off = 1; off < 256; off <<= 1) {
        int t = (threadIdx.x >= off) ? s[threadIdx.x - off] : 0;
        __syncthreads();
        s[threadIdx.x] += t;
        __syncthreads();
    }
    if (i < N_NODES) starts[i] = s[threadIdx.x] - v;
    if (threadIdx.x == 255) bsum[blockIdx.x] = s[255];
}
__global__ __launch_bounds__(256) void k_scan2(int* __restrict__ bsum, int nb) {
    __shared__ int s[256];
    int v = (threadIdx.x < nb) ? bsum[threadIdx.x] : 0;
    s[threadIdx.x] = v; __syncthreads();
#pragma unroll
    for (int off = 1; off < 256; off <<= 1) {
        int t = (threadIdx.x >= off) ? s[threadIdx.x - off] : 0;
        __syncthreads();
        s[threadIdx.x] += t;
        __syncthreads();
    }
    if (threadIdx.x < nb) bsum[threadIdx.x] = s[threadIdx.x] - v;
}

// scatter: NO atomics (p = starts[dst]+bsum[dst>>8]+rank[e]); one 16B record
// {src:int, w0..w3:f16} per edge -> single random cacheline per edge.
__global__ __launch_bounds__(256) void k_scatter(
    const int* __restrict__ ei, const int* __restrict__ starts,
    const int* __restrict__ bsum, const int* __restrict__ rank,
    const float* __restrict__ a_s, const float* __restrict__ a_d,
    int4* __restrict__ rec)
{
    int e = blockIdx.x * 256 + threadIdx.x;
    if (e >= N_EDGES) return;
    int src = ei[e], dst = ei[N_EDGES + e];
    float4 s4 = *(const float4*)(a_s + (size_t)src * HEADS);   // L2-resident (800KB)
    float4 d4 = *(const float4*)(a_d + (size_t)dst * HEADS);
    float w0 = __expf(lrelu(s4.x + d4.x));
    float w1 = __expf(lrelu(s4.y + d4.y));
    float w2 = __expf(lrelu(s4.z + d4.z));
    float w3 = __expf(lrelu(s4.w + d4.w));
    int p = starts[dst] + bsum[dst >> 8] + rank[e];
    int4 r;
    r.x = src;
    r.y = (int)pack_h2(w0, w1);
    r.z = (int)pack_h2(w2, w3);
    r.w = 0;
    rec[p] = r;
}

// gather: one wave per node, lane owns channel pair (2c,2c+1), head = lane>>4.
// Records staged through wave-private LDS: per edge, src is a broadcast
// ds_read_b32 and the weight a 2-address ds_read_u16 (2-way = free) — no
// bpermute chains.
__global__ __launch_bounds__(256) void k_gather(
    const int* __restrict__ starts, const int* __restrict__ bsum,
    const int* __restrict__ counts, const int4* __restrict__ rec,
    const float* __restrict__ a_s, const float* __restrict__ a_d,
    const _Float16* __restrict__ h16, const float* __restrict__ bias,
    const float* __restrict__ gamma, const float* __restrict__ beta,
    float* __restrict__ out)
{
    __shared__ int            lsrc[256];   // [wave*64 + j]
    __shared__ uint2          lw[256];     // 4 packed f16 weights per record

    int gid = blockIdx.x * 256 + threadIdx.x;
    int n = gid >> 6, lane = gid & 63;
    if (n >= N_NODES) return;

    const int wbase = (threadIdx.x >> 6) * 64;     // wave-private LDS region
    const int beg = starts[n] + bsum[n >> 8];
    const int deg = counts[n];
    const int hd = lane >> 4;
    const f16x2* h2 = (const f16x2*)h16;
    const unsigned short* lwh = (const unsigned short*)&lw[wbase];  // [j*4+hd]

    const float wSelf = __expf(lrelu(a_s[n * HEADS + hd] + a_d[n * HEADS + hd]));
    float den = wSelf;
    f16x2 hv = h2[(size_t)n * 64 + lane];
    float acc0 = (float)hv[0] * wSelf;
    float acc1 = (float)hv[1] * wSelf;

    for (int base = 0; base < deg; base += 64) {
        int nc = min(64, deg - base);
        if (lane < nc) {
            int4 rv = rec[beg + base + lane];
            lsrc[wbase + lane] = rv.x;
            lw[wbase + lane] = (uint2){(unsigned)rv.y, (unsigned)rv.z};
        }
        int j = 0;
        for (; j + 8 <= nc; j += 8) {
            int s[8]; float w[8]; f16x2 hh[8];
#pragma unroll
            for (int k = 0; k < 8; ++k) {
                s[k] = lsrc[wbase + j + k];                         // broadcast
                unsigned short uw = lwh[(j + k) * 4 + hd];          // 2-addr, free
                _Float16 wf = *(_Float16*)&uw;
                w[k] = (float)wf;
            }
#pragma unroll
            for (int k = 0; k < 8; ++k) hh[k] = h2[(size_t)s[k] * 64 + lane];
#pragma unroll
            for (int k = 0; k < 8; ++k) {
                acc0 += (float)hh[k][0] * w[k];
                acc1 += (float)hh[k][1] * w[k];
                den  += w[k];
            }
        }
        for (; j < nc; ++j) {
            int s0 = lsrc[wbase + j];
            unsigned short uw = lwh[j * 4 + hd];
            _Float16 wf = *(_Float16*)&uw;
            float w0 = (float)wf;
            f16x2 hx = h2[(size_t)s0 * 64 + lane];
            acc0 += (float)hx[0] * w0;
            acc1 += (float)hx[1] * w0;
            den  += w0;
        }
    }

    // ---- epilogue: normalize + bias + LayerNorm + ELU ----
    float2 bv = ((const float2*)bias)[lane];
    float2 gv = ((const float2*)gamma)[lane];
    float2 be = ((const float2*)beta)[lane];
    float v0 = acc0 / den + bv.x;
    float v1 = acc1 / den + bv.y;
    float s = v0 + v1;
#pragma unroll
    for (int off = 32; off; off >>= 1) s += __shfl_xor(s, off, 64);
    float mu = s * (1.f / 128.f);
    float d0 = v0 - mu, d1 = v1 - mu;
    float q = d0 * d0 + d1 * d1;
#pragma unroll
    for (int off = 32; off; off >>= 1) q += __shfl_xor(q, off, 64);
    float rs = rsqrtf(q * (1.f / 128.f) + LN_EPS);
    float o0 = d0 * rs * gv.x + be.x;
    float o1 = d1 * rs * gv.y + be.y;
    o0 = o0 > 0.f ? o0 : __expf(o0) - 1.f;
    o1 = o1 > 0.f ? o1 : __expf(o1) - 1.f;
    float2 ov = {o0, o1};
    ((float2*)out)[(size_t)n * 64 + lane] = ov;
}

extern "C" void kernel_launch(void* const* d_in, const int* in_sizes, int n_in,
                              void* d_out, int out_size, void* d_ws, size_t ws_size,
                              hipStream_t stream) {
    const float* x       = (const float*)d_in[0];
    const int*   ei      = (const int*)d_in[1];   // [2, E] int32: row0=src, row1=dst
    const float* W       = (const float*)d_in[2];
    const float* att_src = (const float*)d_in[3];
    const float* att_dst = (const float*)d_in[4];
    const float* bias    = (const float*)d_in[5];
    const float* gamma   = (const float*)d_in[6];
    const float* beta    = (const float*)d_in[7];
    float* out = (float*)d_out;

    char* ws = (char*)d_ws;
    // layout (16B-aligned): h16 12.8MB | a_s .8 | a_d .8 | rec 12.8 | rank 3.2
    //                       | counts .2 | starts .2 | bsum 1KB | W16 64KB
    _Float16* h16    = (_Float16*)(ws);
    float*    a_s    = (float*)(ws + 12800000);
    float*    a_d    = (float*)(ws + 13600000);
    int4*     rec    = (int4*) (ws + 14400000);
    int*      rank   = (int*)  (ws + 27200000);
    int*      counts = (int*)  (ws + 30400000);
    int*      starts = (int*)  (ws + 30600000);
    int*      bsum   = (int*)  (ws + 30800000);
    _Float16* W16    = (_Float16*)(ws + 30810240);

    const int NB = (N_NODES + 255) / 256;   // 196

    k0_prep<<<16 + NB, 256, 0, stream>>>(W, W16, counts);
    k1_mfma<<<(N_NODES + 63) / 64, 256, 0, stream>>>(x, W16, att_src, att_dst,
                                                     h16, a_s, a_d);
    k_hist<<<(N_EDGES + 255) / 256, 256, 0, stream>>>(ei, counts, rank);
    k_scan1<<<NB, 256, 0, stream>>>(counts, starts, bsum);
    k_scan2<<<1, 256, 0, stream>>>(bsum, NB);
    k_scatter<<<(N_EDGES + 255) / 256, 256, 0, stream>>>(ei, starts, bsum, rank,
                                                         a_s, a_d, rec);
    k_gather<<<(N_NODES * 64 + 255) / 256, 256, 0, stream>>>(
        starts, bsum, counts, rec, a_s, a_d, h16, bias, gamma, beta, out);
}